// Round 1
// baseline (1759.461 us; speedup 1.0000x reference)
//
#include <hip/hip_runtime.h>

typedef float    f32x4 __attribute__((ext_vector_type(4)));
typedef _Float16 f16x4 __attribute__((ext_vector_type(4)));

#define B_ 256
#define S_ 4096
#define D_ 64
#define H_ 16

// ---------------------------------------------------------------------------
// K1: fused passthrough copy + input projection.
//   xw[b*S+t][j] = bias[j] + sum_d inputs[b][t][d] * W_ih[d][j]
// computed transposed via MFMA: D = A*B + C with
//   A[m=j][k=d] = W_ih[d][j]   (f16, in regs, 4 chained K=16 MFMAs)
//   B[k=d][n]   = x[p0+n][d]   (f16)
//   C[m][n]     = bias[m]
// D(m,n) lands at lane (m>>2)<<4 | n, reg m&3 -> float4 store at xw[p][4*lg..].
// xw is written into the out_hidden region (same size, consumed+overwritten by K2).
// ---------------------------------------------------------------------------
__global__ __launch_bounds__(256) void k1_xw_copy(
    const float* __restrict__ in,       // [B,S,D]
    const float* __restrict__ w_ih,     // [D,H]
    const float* __restrict__ bias,     // [H]
    float* __restrict__ out_inputs,     // [B,S,D] passthrough
    float* __restrict__ xw)             // [B*S,H]  (== out_hidden region)
{
    const int lane = threadIdx.x & 63;
    const int l15  = lane & 15;
    const int lg   = lane >> 4;                       // 0..3
    const int wave = blockIdx.x * (blockDim.x >> 6) + (threadIdx.x >> 6);
    const int nwaves = gridDim.x * (blockDim.x >> 6);

    // A fragments: W_ih^T, four K=16 slices. a[q][e] = W_ih[16q + 4*lg + e][l15]
    f16x4 a[4];
#pragma unroll
    for (int q = 0; q < 4; ++q)
#pragma unroll
        for (int e = 0; e < 4; ++e)
            a[q][e] = (_Float16)w_ih[(16 * q + 4 * lg + e) * H_ + l15];

    f32x4 cbias;
#pragma unroll
    for (int r = 0; r < 4; ++r) cbias[r] = bias[4 * lg + r];

    const int ntiles = (B_ * S_) / 16;                // 65536 row-tiles
    for (int tile = wave; tile < ntiles; tile += nwaves) {
        const long p = (long)tile * 16 + l15;         // flat (b,t) row
        const float* src = in + p * D_ + 4 * lg;
        f32x4 v[4];
#pragma unroll
        for (int q = 0; q < 4; ++q) v[q] = *(const f32x4*)(src + 16 * q);

        float* dst = out_inputs + p * D_ + 4 * lg;    // passthrough
#pragma unroll
        for (int q = 0; q < 4; ++q) *(f32x4*)(dst + 16 * q) = v[q];

        f32x4 d = cbias;
#pragma unroll
        for (int q = 0; q < 4; ++q) {
            f16x4 b;
#pragma unroll
            for (int e = 0; e < 4; ++e) b[e] = (_Float16)v[q][e];
            d = __builtin_amdgcn_mfma_f32_16x16x16f16(a[q], b, d, 0, 0, 0);
        }
        // D(m=j, n=l15) -> xw[p][j], lane holds j = 4*lg..4*lg+3 contiguous
        *(f32x4*)(xw + p * H_ + 4 * lg) = d;
    }
}

// ---------------------------------------------------------------------------
// K2: serial scan. One wave per 16-batch group (16 waves total).
//   D = W_hh^T * h^T + xw_t   (per step), relu, D feeds next step's B directly
//   (D layout == B layout under m<->k), hidden stored as fp32 pre-rounding.
//   output[b][t] = dot(hidden, linear_w) + linear_b via 2 shfl_xor reduce.
// ---------------------------------------------------------------------------
__global__ __launch_bounds__(64) void k2_scan(
    const float* __restrict__ w_hh,     // [H,H]
    const float* __restrict__ lw,       // [1,H]
    const float* __restrict__ lb,       // [1]
    float* __restrict__ out_output,     // [B,S]
    float* __restrict__ hid)            // [B*S,H]: xw on entry, hidden on exit
{
    const int lane = threadIdx.x & 63;
    const int l15  = lane & 15;
    const int lg   = lane >> 4;
    const int b0   = blockIdx.x * 16;

    // A = W_hh^T: wa[e] = W_hh[4*lg+e][l15]
    f16x4 wa;
#pragma unroll
    for (int e = 0; e < 4; ++e)
        wa[e] = (_Float16)w_hh[(4 * lg + e) * H_ + l15];

    f32x4 lwf;
#pragma unroll
    for (int r = 0; r < 4; ++r) lwf[r] = lw[4 * lg + r];
    const float lbv = lb[0];

    f16x4 h;
#pragma unroll
    for (int e = 0; e < 4; ++e) h[e] = (_Float16)0.0f;

    float* ptr  = hid + (long)(b0 + l15) * S_ * H_ + 4 * lg;
    float* optr = out_output + (long)(b0 + l15) * S_;

    f32x4 c_cur = *(const f32x4*)ptr;                 // xw_0
    for (int t = 0; t < S_; ++t) {
        // prefetch next step's xw (final iter reads one row past: still inside
        // d_out — value discarded)
        f32x4 c_next = *(const f32x4*)(ptr + H_);

        f32x4 d = __builtin_amdgcn_mfma_f32_16x16x16f16(wa, h, c_cur, 0, 0, 0);
#pragma unroll
        for (int r = 0; r < 4; ++r) d[r] = fmaxf(d[r], 0.0f);

        *(f32x4*)ptr = d;                             // hidden (fp32, exact)
#pragma unroll
        for (int e = 0; e < 4; ++e) h[e] = (_Float16)d[e];  // next B operand

        // output head: partial dot, reduce across the 4 lane-groups
        float psum = d[0] * lwf[0] + d[1] * lwf[1] + d[2] * lwf[2] + d[3] * lwf[3];
        psum += __shfl_xor(psum, 16, 64);
        psum += __shfl_xor(psum, 32, 64);
        if (lg == 0) optr[t] = psum + lbv;

        c_cur = c_next;
        ptr += H_;
    }
}

extern "C" void kernel_launch(void* const* d_in, const int* in_sizes, int n_in,
                              void* d_out, int out_size, void* d_ws, size_t ws_size,
                              hipStream_t stream) {
    const float* inputs = (const float*)d_in[0];
    const float* w_ih   = (const float*)d_in[1];
    const float* w_hh   = (const float*)d_in[2];
    const float* bias   = (const float*)d_in[3];
    const float* lw     = (const float*)d_in[4];
    const float* lb     = (const float*)d_in[5];

    float* out        = (float*)d_out;
    float* out_output = out;                                     // B*S
    float* out_hidden = out + (long)B_ * S_;                     // B*S*H
    float* out_inputs = out + (long)B_ * S_ + (long)B_ * S_ * H_; // B*S*D

    k1_xw_copy<<<512, 256, 0, stream>>>(inputs, w_ih, bias, out_inputs, out_hidden);
    k2_scan<<<16, 64, 0, stream>>>(w_hh, lw, lb, out_output, out_hidden);
}

// Round 2
// 1111.654 us; speedup vs baseline: 1.5827x; 1.5827x over previous
//
#include <hip/hip_runtime.h>

typedef float    f32x4 __attribute__((ext_vector_type(4)));
typedef _Float16 f16x4 __attribute__((ext_vector_type(4)));

#define B_ 256
#define S_ 4096
#define D_ 64
#define H_ 16
#define UN 4      // K1: tiles per wave iteration (independent MFMA chains)
#define NP 16     // K2: prefetch depth (register ring, fully unrolled)

// ---------------------------------------------------------------------------
// K1: fused passthrough copy + input projection, 4 tiles in flight per wave.
//   xw[p][j] = bias[j] + sum_d in[p][d] * W_ih[d][j]  via transposed MFMA.
//   D(m=j,n=row) layout: lane (m>>2)<<4|n, reg m&3 -> float4 store xw[p][4lg..].
// ---------------------------------------------------------------------------
__global__ __launch_bounds__(256) void k1_xw_copy(
    const float* __restrict__ in,       // [B,S,D]
    const float* __restrict__ w_ih,     // [D,H]
    const float* __restrict__ bias,     // [H]
    float* __restrict__ out_inputs,     // [B,S,D] passthrough
    float* __restrict__ xw)             // [B*S,H]  (== out_hidden region)
{
    const int lane = threadIdx.x & 63;
    const int l15  = lane & 15;
    const int lg   = lane >> 4;                       // 0..3
    const int wave = blockIdx.x * (blockDim.x >> 6) + (threadIdx.x >> 6);
    const int nwaves = gridDim.x * (blockDim.x >> 6);

    // A fragments: a[q][e] = W_ih[16q + 4lg + e][l15]
    f16x4 a[4];
#pragma unroll
    for (int q = 0; q < 4; ++q)
#pragma unroll
        for (int e = 0; e < 4; ++e)
            a[q][e] = (_Float16)w_ih[(16 * q + 4 * lg + e) * H_ + l15];

    f32x4 cbias;
#pragma unroll
    for (int r = 0; r < 4; ++r) cbias[r] = bias[4 * lg + r];

    const int ntiles = (B_ * S_) / 16;                // 65536 row-tiles
    for (int t0 = wave * UN; t0 < ntiles; t0 += nwaves * UN) {
        f32x4 v[UN][4];
#pragma unroll
        for (int u = 0; u < UN; ++u) {
            const long p = (long)(t0 + u) * 16 + l15;
            const float* src = in + p * D_ + 4 * lg;
#pragma unroll
            for (int q = 0; q < 4; ++q) v[u][q] = *(const f32x4*)(src + 16 * q);
        }
#pragma unroll
        for (int u = 0; u < UN; ++u) {
            const long p = (long)(t0 + u) * 16 + l15;
            float* dst = out_inputs + p * D_ + 4 * lg;
#pragma unroll
            for (int q = 0; q < 4; ++q) *(f32x4*)(dst + 16 * q) = v[u][q];
        }
        f32x4 d[UN];
#pragma unroll
        for (int u = 0; u < UN; ++u) {
            d[u] = cbias;
#pragma unroll
            for (int q = 0; q < 4; ++q) {
                f16x4 b;
#pragma unroll
                for (int e = 0; e < 4; ++e) b[e] = (_Float16)v[u][q][e];
                d[u] = __builtin_amdgcn_mfma_f32_16x16x16f16(a[q], b, d[u], 0, 0, 0);
            }
        }
#pragma unroll
        for (int u = 0; u < UN; ++u) {
            const long p = (long)(t0 + u) * 16 + l15;
            *(f32x4*)(xw + p * H_ + 4 * lg) = d[u];
        }
    }
}

// ---------------------------------------------------------------------------
// K2: serial scan, 16-deep register-ring prefetch of xw.
//   D = W_hh^T * h^T + xw_t, relu; D layout == next B layout (zero shuffle).
//   xw lives in out_hidden and is overwritten in place by fp32 hidden
//   (same lane, same address, consumed before overwrite -> race-free).
//   Past-end prefetch reads spill into the out_inputs region (valid memory,
//   values discarded).
// ---------------------------------------------------------------------------
__global__ __launch_bounds__(64) void k2_scan(
    const float* __restrict__ w_hh,     // [H,H]
    const float* __restrict__ lw,       // [1,H]
    const float* __restrict__ lb,       // [1]
    float* __restrict__ out_output,     // [B,S]
    float* __restrict__ hid)            // [B*S,H]: xw on entry, hidden on exit
{
    const int lane = threadIdx.x & 63;
    const int l15  = lane & 15;
    const int lg   = lane >> 4;
    const int b0   = blockIdx.x * 16;

    // A = W_hh^T: wa[e] = W_hh[4lg+e][l15]
    f16x4 wa;
#pragma unroll
    for (int e = 0; e < 4; ++e)
        wa[e] = (_Float16)w_hh[(4 * lg + e) * H_ + l15];

    f32x4 lwf;
#pragma unroll
    for (int r = 0; r < 4; ++r) lwf[r] = lw[4 * lg + r];
    const float lbv = lb[0];

    f16x4 h;
#pragma unroll
    for (int e = 0; e < 4; ++e) h[e] = (_Float16)0.0f;

    float* ptr  = hid + (long)(b0 + l15) * S_ * H_ + 4 * lg;  // row t at ptr + t*H_
    float* optr = out_output + (long)(b0 + l15) * S_;

    // prologue: fill the ring with xw rows 0..NP-1
    f32x4 ring[NP];
#pragma unroll
    for (int i = 0; i < NP; ++i) ring[i] = *(const f32x4*)(ptr + (long)i * H_);

    for (int tb = 0; tb < S_; tb += NP) {
#pragma unroll
        for (int u = 0; u < NP; ++u) {
            const int t = tb + u;
            f32x4 c = ring[u];
            // prefetch row t+NP (static ring index; tail reads are in-bounds
            // of d_out and discarded)
            ring[u] = *(const f32x4*)(ptr + (long)(t + NP) * H_);

            f32x4 d = __builtin_amdgcn_mfma_f32_16x16x16f16(wa, h, c, 0, 0, 0);
#pragma unroll
            for (int r = 0; r < 4; ++r) d[r] = fmaxf(d[r], 0.0f);

            *(f32x4*)(ptr + (long)t * H_) = d;                 // fp32 hidden
#pragma unroll
            for (int e = 0; e < 4; ++e) h[e] = (_Float16)d[e]; // next B operand

            float psum = d[0] * lwf[0] + d[1] * lwf[1] + d[2] * lwf[2] + d[3] * lwf[3];
            psum += __shfl_xor(psum, 16, 64);
            psum += __shfl_xor(psum, 32, 64);
            if (lg == 0) optr[t] = psum + lbv;
        }
    }
}

extern "C" void kernel_launch(void* const* d_in, const int* in_sizes, int n_in,
                              void* d_out, int out_size, void* d_ws, size_t ws_size,
                              hipStream_t stream) {
    const float* inputs = (const float*)d_in[0];
    const float* w_ih   = (const float*)d_in[1];
    const float* w_hh   = (const float*)d_in[2];
    const float* bias   = (const float*)d_in[3];
    const float* lw     = (const float*)d_in[4];
    const float* lb     = (const float*)d_in[5];

    float* out        = (float*)d_out;
    float* out_output = out;                                      // B*S
    float* out_hidden = out + (long)B_ * S_;                      // B*S*H
    float* out_inputs = out + (long)B_ * S_ + (long)B_ * S_ * H_; // B*S*D

    k1_xw_copy<<<1024, 256, 0, stream>>>(inputs, w_ih, bias, out_inputs, out_hidden);
    k2_scan<<<16, 64, 0, stream>>>(w_hh, lw, lb, out_output, out_hidden);
}